// Round 7
// baseline (258.678 us; speedup 1.0000x reference)
//
#include <hip/hip_runtime.h>
#include <stdint.h>

#define B_      16
#define F_      257
#define T_      8000
#define NB_     64
#define TT_     64
#define NTILES  125
#define TPC     2      // body tiles per chunk
#define NCHUNK  63     // 16 b x 63 chunks = 1008 blocks
#define WTILES  2      // 128 warm-up steps; contraction 0.9526^128 ~ 2e-3
#define LDSW    40     // [f][t] staging row stride (u16): 32 t + 8 pad; 20-dword bank rot

typedef __attribute__((ext_vector_type(8))) short short8;
typedef __attribute__((ext_vector_type(4))) float floatx4;

__device__ __forceinline__ unsigned fbits(float x) {
    union { float f; unsigned u; } v; v.f = x; return v.u;
}
__device__ __forceinline__ float ubits(unsigned u) {
    union { float f; unsigned u; } v; v.u = u; return v.f;
}
__device__ __forceinline__ unsigned short f2bf_rne(float x) {
    unsigned u = fbits(x);
    unsigned r = u + 0x7FFFu + ((u >> 16) & 1u);
    return (unsigned short)(r >> 16);
}
// pack truncated bf16 pair (1 v_perm_b32): low16 = hi16(a), high16 = hi16(b)
__device__ __forceinline__ unsigned packbf(float a, float b) {
    return __builtin_amdgcn_perm(fbits(b), fbits(a), 0x07060302u);
}

// vnr region: bf16 [t][f], idx16 = t*256 + (f ^ (st(t)<<3)), st = ((t&3)<<2)|((t>>2)&3)
// (8-elem-granular XOR: einsum b128 frags contiguous; scan vnr writes 2-way free)
__device__ __forceinline__ int stidx(int t, int f) {
    const int st = ((t & 3) << 2) | ((t >> 2) & 3);
    return t * 256 + (f ^ (st << 3));
}
// staging region: bf16 [f][t-half], chunk c (8 u16) at LDSW*f + 8*(c ^ ((f>>3)&3))
// -> row reads: lanes f, f+32 collide only (2-way, free); writes <=2-way.

template<bool BODY, bool DO256>
static __device__ __forceinline__ void scan_half(
    unsigned short* __restrict__ vnrR, const unsigned short* __restrict__ stg,
    float* __restrict__ vnr256s, const int f_own, const int h,
    float& nf, const float floorv, float& nf256, const float floor256,
    const float rise, const float fall, const float ns)
{
    const int g2    = (f_own >> 3) & 3;
    const int rbase = LDSW * f_own;
    uint4 cur = *(const uint4*)&stg[rbase + 8 * (0 ^ g2)];
    uint4 c256;
    if (DO256) c256 = *(const uint4*)&stg[LDSW * 256 + 0];
    float nfl = nf;
    float nl  = nf256;
    #pragma unroll
    for (int c = 0; c < 4; ++c) {
        uint4 nxt, n256;
        if (c < 3) {
            nxt = *(const uint4*)&stg[rbase + 8 * ((c + 1) ^ g2)];
            if (DO256) n256 = *(const uint4*)&stg[LDSW * 256 + 8 * (c + 1)];
        }
        #pragma unroll
        for (int u = 0; u < 8; ++u) {
            const int j = h * 32 + c * 8 + u;
            const unsigned uu = ((const unsigned*)&cur)[u >> 1];
            const float x = ubits((u & 1) ? (uu & 0xFFFF0000u) : (uu << 16));
            const float d = x - nfl;
            nfl = fmaxf(fmaxf(__builtin_fmaf(rise, d, nfl),
                              __builtin_fmaf(fall, d, nfl)), floorv);
            if (BODY) {
                const float vnr = x * __builtin_amdgcn_rcpf(
                                      __builtin_fmaf(ns, nfl, 1e-8f));
                vnrR[stidx(j, f_own)] = (unsigned short)(fbits(vnr) >> 16);
            }
            if (DO256) {   // all lanes of wave 0: identical broadcast chain
                const unsigned vv = ((const unsigned*)&c256)[u >> 1];
                const float x2 = ubits((u & 1) ? (vv & 0xFFFF0000u) : (vv << 16));
                const float d2 = x2 - nl;
                nl = fmaxf(fmaxf(__builtin_fmaf(rise, d2, nl),
                                 __builtin_fmaf(fall, d2, nl)), floor256);
                if (BODY) vnr256s[j] = x2 * __builtin_amdgcn_rcpf(
                                            __builtin_fmaf(ns, nl, 1e-8f));
            }
        }
        if (c < 3) { cur = nxt; if (DO256) c256 = n256; }
    }
    nf = nfl;
    if (DO256) nf256 = nl;
}

__global__ __launch_bounds__(256, 3) void vnr_fused_kernel(
    const float* __restrict__ mag, const float* __restrict__ fb,
    const float* __restrict__ p_ns, const float* __restrict__ p_rr,
    const float* __restrict__ p_rf, float* __restrict__ out)
{
    __shared__ unsigned short vnrR[64 * 256];   // 32 KB (einsum B operand)
    __shared__ unsigned short stg[F_ * LDSW];   // 20.1 KB (half-tile staging)
    __shared__ float vnr256s[64];

    const int tid  = threadIdx.x;
    const int lane = tid & 63;
    const int w    = tid >> 6;
    const int l15  = tid & 15;
    const int q    = (tid & 63) >> 4;
    const int r8   = lane >> 3;   // staging row-in-pass
    const int s8   = lane & 7;    // staging t-slot (4 t)
    const bool w0  = (w == 0);

    const int bid = blockIdx.x;
    const int b   = bid & 15;
    const int c   = bid >> 4;

    const float ns   = fabsf(p_ns[0]);
    const float rise = 1.0f / (1.0f + __expf(-p_rr[0]));
    const float fall = 1.0f / (1.0f + __expf(-p_rf[0]));

    const float* magp = mag + (size_t)b * (size_t)F_ * (size_t)T_;

    // ---- A fragments (fb) in VGPRs ----
    short8 afrag[8];
    {
        const float* fbrow = fb + (16 * w + l15) * F_;
        #pragma unroll
        for (int kt = 0; kt < 8; ++kt) {
            const int f0 = 32 * kt + 8 * q;
            short8 a;
            #pragma unroll
            for (int j = 0; j < 8; ++j) a[j] = (short)f2bf_rne(fbrow[f0 + j]);
            afrag[kt] = a;
        }
    }
    float fb256[4];
    #pragma unroll
    for (int r = 0; r < 4; ++r) fb256[r] = fb[(16 * w + 4 * q + r) * F_ + 256];

    // ---- init_min over first 20 frames (exact fp32) ----
    const int f_own = tid;
    float mn = 1e30f;
    #pragma unroll
    for (int t = 0; t < 20; ++t) mn = fminf(mn, magp[(size_t)f_own * T_ + t]);
    const float initv  = fmaxf(mn, 1e-5f);
    const float floorv = 0.5f * initv;
    float nf = initv;

    float nf256 = 0.f, floor256 = 0.f;
    if (w0) {   // broadcast loads; all wave-0 lanes identical
        float m2 = 1e30f;
        #pragma unroll
        for (int t = 0; t < 20; ++t) m2 = fminf(m2, magp[(size_t)256 * T_ + t]);
        const float iv = fmaxf(m2, 1e-5f);
        nf256 = iv; floor256 = 0.5f * iv;
    }

    const int bodyBeg = TPC * c;
    const int tileBeg = (c == 0) ? 0 : max(0, bodyBeg - WTILES);
    const int tileEnd = min(bodyBeg + TPC, NTILES);

    float4 ldv[8];
    float4 ld256;

    #define ISSUE_HALF(TILE, H)                                               \
        do {                                                                  \
            _Pragma("unroll")                                                 \
            for (int p = 0; p < 8; ++p) {                                     \
                const int f = 64 * w + 8 * p + r8;                            \
                ldv[p] = *(const float4*)&magp[(size_t)f * T_ +               \
                              (TILE) * TT_ + (H) * 32 + 4 * s8];              \
            }                                                                 \
            if (w0 && lane < 8)                                               \
                ld256 = *(const float4*)&magp[(size_t)256 * T_ +              \
                              (TILE) * TT_ + (H) * 32 + 4 * lane];            \
        } while (0)

    #define PACK_WRITE()                                                      \
        do {                                                                  \
            _Pragma("unroll")                                                 \
            for (int p = 0; p < 8; ++p) {                                     \
                const int f   = 64 * w + 8 * p + r8;                          \
                const int g2f = (8 * w + p) & 3;                              \
                const int idx = LDSW * f + 8 * ((s8 >> 1) ^ g2f) + 4 * (s8 & 1); \
                *(uint2*)&stg[idx] = make_uint2(packbf(ldv[p].x, ldv[p].y),   \
                                                packbf(ldv[p].z, ldv[p].w));  \
            }                                                                 \
            if (w0 && lane < 8) {                                             \
                const int idx = LDSW * 256 + 8 * (lane >> 1) + 4 * (lane & 1);\
                *(uint2*)&stg[idx] = make_uint2(packbf(ld256.x, ld256.y),     \
                                                packbf(ld256.z, ld256.w));    \
            }                                                                 \
        } while (0)

    #define SCAN(H, BODYF)                                                    \
        do {                                                                  \
            if (BODYF) { if (w0) scan_half<true,  true >(vnrR, stg, vnr256s, f_own, H, nf, floorv, nf256, floor256, rise, fall, ns); \
                         else    scan_half<true,  false>(vnrR, stg, vnr256s, f_own, H, nf, floorv, nf256, floor256, rise, fall, ns); } \
            else       { if (w0) scan_half<false, true >(vnrR, stg, vnr256s, f_own, H, nf, floorv, nf256, floor256, rise, fall, ns); \
                         else    scan_half<false, false>(vnrR, stg, vnr256s, f_own, H, nf, floorv, nf256, floor256, rise, fall, ns); } \
        } while (0)

    bool prevBody = false;
    ISSUE_HALF(tileBeg, 0);   // prime

    for (int tile = tileBeg; tile < tileEnd; ++tile) {
        const bool body = (tile >= bodyBeg);
        const int t0 = tile * TT_;

        PACK_WRITE();              // stg only — safe during prev einsum (disjoint)
        ISSUE_HALF(tile, 1);       // half B in flight under scan A
        if (prevBody) __syncthreads();   // prev einsum readers done (vnrR writes next)
        SCAN(0, body);

        PACK_WRITE();              // half B (scan-A reads precede: in-order per wave)
        {
            const int tnext = (tile + 1 < tileEnd) ? tile + 1 : tile;
            ISSUE_HALF(tnext, 0);  // next tile's half A in flight across barrier
        }
        SCAN(1, body);

        prevBody = body;
        if (!body) continue;       // warm-up: zero barriers

        __syncthreads();           // all vnrR rows + vnr256s complete

        // ---- einsum via MFMA (layouts unchanged from r4-r6) ----
        const int stl3 = ((((l15 & 3) << 2) | (l15 >> 2)) << 3);
        floatx4 acc[4];
        #pragma unroll
        for (int tt = 0; tt < 4; ++tt) acc[tt] = (floatx4){0.f, 0.f, 0.f, 0.f};
        #pragma unroll
        for (int kt = 0; kt < 8; ++kt) {
            #pragma unroll
            for (int tt = 0; tt < 4; ++tt) {
                const int t = tt * 16 + l15;
                const short8* bp = (const short8*)
                    &vnrR[t * 256 + ((32 * kt + 8 * q) ^ stl3)];
                acc[tt] = __builtin_amdgcn_mfma_f32_16x16x32_bf16(afrag[kt], *bp, acc[tt], 0, 0, 0);
            }
        }
        const size_t outb = (size_t)b * NB_ * T_;
        #pragma unroll
        for (int tt = 0; tt < 4; ++tt) {
            const int t = tt * 16 + l15;
            const float v256 = vnr256s[t];
            #pragma unroll
            for (int r = 0; r < 4; ++r) {
                const float sv = acc[tt][r] + fb256[r] * v256;       // sv >= 0
                const float e  = __expf(sv * 0.2f);
                const float y  = 1.0f - 2.0f * __builtin_amdgcn_rcpf(e + 1.0f);
                out[outb + (size_t)(16 * w + 4 * q + r) * T_ + (size_t)(t0 + t)] = y;
            }
        }
        // no post-einsum barrier: next tile's stg writes are disjoint from vnrR;
        // next vnrR writes are guarded by the prevBody barrier above.
    }
    #undef ISSUE_HALF
    #undef PACK_WRITE
    #undef SCAN
}

extern "C" void kernel_launch(void* const* d_in, const int* in_sizes, int n_in,
                              void* d_out, int out_size, void* d_ws, size_t ws_size,
                              hipStream_t stream) {
    (void)in_sizes; (void)n_in; (void)d_ws; (void)ws_size; (void)out_size;
    const float* mag = (const float*)d_in[0];
    const float* fbp = (const float*)d_in[1];
    const float* nsp = (const float*)d_in[2];
    const float* rr  = (const float*)d_in[3];
    const float* rf  = (const float*)d_in[4];
    float* outp = (float*)d_out;

    dim3 grid(B_ * NCHUNK);   // 1008 blocks = 16 b x 63 chunks, 3 blocks/CU (LDS)
    dim3 block(256);
    hipLaunchKernelGGL(vnr_fused_kernel, grid, block, 0, stream, mag, fbp, nsp, rr, rf, outp);
}